// Round 4
// baseline (817.787 us; speedup 1.0000x reference)
//
#include <hip/hip_runtime.h>
#include <hip/hip_bf16.h>

typedef __bf16 bf16x8 __attribute__((ext_vector_type(8)));
typedef float  f32x4  __attribute__((ext_vector_type(4)));

#define SCALE_QK 0.17677669529663687f   // 1/sqrt(32)
#define MFMA(a, b, c) __builtin_amdgcn_mfma_f32_16x16x32_bf16((a), (b), (c), 0, 0, 0)

__device__ __forceinline__ float b2f(ushort u) {
    __hip_bfloat16 h; *reinterpret_cast<ushort*>(&h) = u; return __bfloat162float(h);
}
__device__ __forceinline__ ushort f2b(float f) {
    __hip_bfloat16 h = __float2bfloat16(f); return *reinterpret_cast<ushort*>(&h);
}
__device__ __forceinline__ bf16x8 ld8(const ushort* p) {
    union { uint4 v; bf16x8 f; } u; u.v = *(const uint4*)p; return u.f;
}
__device__ __forceinline__ void split8(float4 a0, float4 a1, bf16x8& hi, bf16x8& lo) {
    float av[8] = {a0.x, a0.y, a0.z, a0.w, a1.x, a1.y, a1.z, a1.w};
    union { bf16x8 f; ushort u[8]; } H, L;
#pragma unroll
    for (int i = 0; i < 8; ++i) {
        ushort h = f2b(av[i]);
        H.u[i] = h;
        L.u[i] = f2b(av[i] - b2f(h));
    }
    hi = H.f; lo = L.f;
}

// ---------------------------------------------------------------------------
// K0: weight prep (fp32 in HBM).
//  Wq,Wk (512x128) -> transposed hi/lo bf16 (128x512 each)
//  Wv (512x128)    -> transposed bf16 (128x512)
//  Wqo (128x512)   -> transposed bf16 (512x128)
//  Wo (128x512)    -> bf16 copy
// ---------------------------------------------------------------------------
__global__ void k_prep(const float* __restrict__ Wq, const float* __restrict__ Wk,
                       const float* __restrict__ Wv, const float* __restrict__ Wqo,
                       const float* __restrict__ Wo,
                       ushort* __restrict__ WqThi, ushort* __restrict__ WqTlo,
                       ushort* __restrict__ WkThi, ushort* __restrict__ WkTlo,
                       ushort* __restrict__ WvT,  ushort* __restrict__ WqoT,
                       ushort* __restrict__ WoB) {
    int idx = blockIdx.x * 256 + threadIdx.x;   // 5 * 65536 total
    int mat = idx >> 16, i = idx & 65535;
    if (mat == 0) {
        int n = i >> 9, k = i & 511;
        float w = Wq[k * 128 + n];
        ushort hi = f2b(w);
        WqThi[i] = hi; WqTlo[i] = f2b(w - b2f(hi));
    } else if (mat == 1) {
        int n = i >> 9, k = i & 511;
        float w = Wk[k * 128 + n];
        ushort hi = f2b(w);
        WkThi[i] = hi; WkTlo[i] = f2b(w - b2f(hi));
    } else if (mat == 2) {
        int n = i >> 9, k = i & 511;
        WvT[i] = f2b(Wv[k * 128 + n]);
    } else if (mat == 3) {
        int n = i >> 7, k = i & 127;
        WqoT[i] = f2b(Wqo[k * 512 + n]);
    } else if (mat == 4) {
        WoB[i] = f2b(Wo[i]);
    }
}

// ---------------------------------------------------------------------------
// K1: Q projection, LDS-free split-bf16 GEMM.
// Wave = 16 rows x 128 cols; block = 4 waves = 64 rows; grid 1024 -> 16 waves/CU.
// A frag loaded directly from global fp32 (2x float4) + in-register hi/lo split;
// B frags (pre-split bf16) loaded per-j from L1/L2.  No LDS, no barriers.
// ---------------------------------------------------------------------------
__global__ __launch_bounds__(256) void k_proj_q(
        const float* __restrict__ A, const ushort* __restrict__ BThi,
        const ushort* __restrict__ BTlo, const float* __restrict__ bias,
        float* __restrict__ outF, ushort* __restrict__ outB) {
    const int tid = threadIdx.x;
    const int w = tid >> 6, lane = tid & 63;
    const int quad = lane >> 4, l16 = lane & 15;
    const int wrow0 = blockIdx.x * 64 + w * 16;
    const float* Ar = A + (size_t)(wrow0 + l16) * 512 + quad * 8;

    f32x4 acc[8] = {};

    for (int k0 = 0; k0 < 512; k0 += 32) {
        float4 a0 = *(const float4*)(Ar + k0);
        float4 a1 = *(const float4*)(Ar + k0 + 4);
        bf16x8 aH, aL;
        split8(a0, a1, aH, aL);
        const int bofs = k0 + quad * 8;
#pragma unroll
        for (int j = 0; j < 8; ++j) {
            const size_t bro = (size_t)(j * 16 + l16) * 512 + bofs;
            bf16x8 bH = ld8(&BThi[bro]);
            bf16x8 bL = ld8(&BTlo[bro]);
            acc[j] = MFMA(aL, bH, acc[j]);
            acc[j] = MFMA(aH, bL, acc[j]);
            acc[j] = MFMA(aH, bH, acc[j]);
        }
    }

    const int rbase = wrow0 + quad * 4;    // C/D: row = quad*4 + r, col = j*16+l16
#pragma unroll
    for (int j = 0; j < 8; ++j) {
        int col = j * 16 + l16;
        float bv = bias[col];
#pragma unroll
        for (int r = 0; r < 4; ++r) {
            float v = acc[j][r] + bv;
            outF[(size_t)(rbase + r) * 128 + col] = v;
            outB[(size_t)(rbase + r) * 128 + col] = f2b(v);
        }
    }
}

// ---------------------------------------------------------------------------
// K2: fused K(split) + V(plain) projection, LDS-free.  Reads KVin once.
// V's bf16 A-operand is the hi part of the split decomposition.
// ---------------------------------------------------------------------------
__global__ __launch_bounds__(256) void k_proj_kv(
        const float* __restrict__ A,
        const ushort* __restrict__ BKhi, const ushort* __restrict__ BKlo,
        const ushort* __restrict__ BV,
        const float* __restrict__ biasK, const float* __restrict__ biasV,
        float* __restrict__ KmF, ushort* __restrict__ VmB) {
    const int tid = threadIdx.x;
    const int w = tid >> 6, lane = tid & 63;
    const int quad = lane >> 4, l16 = lane & 15;
    const int wrow0 = blockIdx.x * 64 + w * 16;
    const float* Ar = A + (size_t)(wrow0 + l16) * 512 + quad * 8;

    f32x4 accK[8] = {};
    f32x4 accV[8] = {};

    for (int k0 = 0; k0 < 512; k0 += 32) {
        float4 a0 = *(const float4*)(Ar + k0);
        float4 a1 = *(const float4*)(Ar + k0 + 4);
        bf16x8 aH, aL;
        split8(a0, a1, aH, aL);
        const int bofs = k0 + quad * 8;
#pragma unroll
        for (int j = 0; j < 8; ++j) {
            const size_t bro = (size_t)(j * 16 + l16) * 512 + bofs;
            bf16x8 bH = ld8(&BKhi[bro]);
            bf16x8 bL = ld8(&BKlo[bro]);
            bf16x8 bV = ld8(&BV[bro]);
            accK[j] = MFMA(aL, bH, accK[j]);
            accK[j] = MFMA(aH, bL, accK[j]);
            accK[j] = MFMA(aH, bH, accK[j]);
            accV[j] = MFMA(aH, bV, accV[j]);
        }
    }

    const int rbase = wrow0 + quad * 4;
#pragma unroll
    for (int j = 0; j < 8; ++j) {
        int col = j * 16 + l16;
        float bk = biasK[col], bv = biasV[col];
#pragma unroll
        for (int r = 0; r < 4; ++r) {
            KmF[(size_t)(rbase + r) * 128 + col] = accK[j][r] + bk;
            VmB[(size_t)(rbase + r) * 128 + col] = f2b(accV[j][r] + bv);
        }
    }
}

// ---------------------------------------------------------------------------
// K3: score partials, fp32 VALU.
// partial[sp][b*4+h][d][e] = sum_{l in split of 64} Qm[l][hd]*Km[l][he]
// grid (16 b, 64 splits) = 1024 blocks.
// ---------------------------------------------------------------------------
__global__ __launch_bounds__(256) void k_scores(
        const float* __restrict__ Qm, const float* __restrict__ Km,
        float* __restrict__ partial) {
    int b = blockIdx.x, sp = blockIdx.y;
    int t = threadIdx.x;
    int h = t >> 6, tl = t & 63;
    int d0 = (tl >> 3) * 4, e0 = (tl & 7) * 4;
    const float* Qb = Qm + ((size_t)b * 4096 + sp * 64) * 128 + h * 32 + d0;
    const float* Kb = Km + ((size_t)b * 4096 + sp * 64) * 128 + h * 32 + e0;
    float acc[4][4] = {};
#pragma unroll 8
    for (int l = 0; l < 64; ++l) {
        float4 q4 = *(const float4*)(Qb + (size_t)l * 128);
        float4 k4 = *(const float4*)(Kb + (size_t)l * 128);
        float q[4] = {q4.x, q4.y, q4.z, q4.w};
        float k[4] = {k4.x, k4.y, k4.z, k4.w};
#pragma unroll
        for (int i = 0; i < 4; ++i)
#pragma unroll
            for (int j = 0; j < 4; ++j) acc[i][j] += q[i] * k[j];
    }
    float* P = partial + ((size_t)(sp * 64 + b * 4 + h)) * 1024;
#pragma unroll
    for (int i = 0; i < 4; ++i)
#pragma unroll
        for (int j = 0; j < 4; ++j)
            P[(d0 + i) * 32 + e0 + j] = acc[i][j];
}

// ---------------------------------------------------------------------------
// K4: fused partial-reduce + softmax + Wc build.  One block per (b,h).
// attn fp32 -> d_out tail; WcT[b][m][h*32+e] = sum_d attn*Wo (bf16).
// ---------------------------------------------------------------------------
__global__ __launch_bounds__(256) void k_attn(
        const float* __restrict__ partial, const ushort* __restrict__ WoB,
        float* __restrict__ attnOut, ushort* __restrict__ WcT) {
    int bh = blockIdx.x; int b = bh >> 2, h = bh & 3;
    __shared__ float aS[1024];
    __shared__ __align__(16) ushort wS[32 * 512];
    int t = threadIdx.x;
    for (int i = t; i < 1024; i += 256) {
        float s = 0.f;
#pragma unroll
        for (int sp = 0; sp < 64; ++sp)
            s += partial[(size_t)(sp * 64 + bh) * 1024 + i];
        aS[i] = s * SCALE_QK;
    }
    for (int i = t; i < 2048; i += 256) {
        int r = i >> 6, c = (i & 63) * 8;
        *(uint4*)&wS[r * 512 + c] = *(const uint4*)&WoB[(size_t)(h * 32 + r) * 512 + c];
    }
    __syncthreads();
    if (t < 32) {
        float m = -1e30f;
#pragma unroll
        for (int e = 0; e < 32; ++e) m = fmaxf(m, aS[t * 32 + e]);
        float p[32]; float sum = 0.f;
#pragma unroll
        for (int e = 0; e < 32; ++e) { p[e] = __expf(aS[t * 32 + e] - m); sum += p[e]; }
        float inv = 1.f / sum;
#pragma unroll
        for (int e = 0; e < 32; ++e) aS[t * 32 + e] = p[e] * inv;
    }
    __syncthreads();
    for (int i = t; i < 1024; i += 256)
        attnOut[(size_t)bh * 1024 + i] = aS[i];
    int e = t & 31, mg = t >> 5;
    for (int mi = 0; mi < 64; ++mi) {
        int m = mg * 64 + mi;
        float acc = 0.f;
#pragma unroll
        for (int d = 0; d < 32; ++d)
            acc += aS[d * 32 + e] * b2f(wS[d * 512 + m]);
        WcT[((size_t)b * 512 + m) * 128 + h * 32 + e] = f2b(acc);
    }
}

// ---------------------------------------------------------------------------
// K5: fused output GEMM + LayerNorm, LDS-free.
// Wave = 16 rows x 512 cols (32 j-frags); block = 4 waves = 64 rows.
// x = Vm @ Wc_b + Qm @ Wqo + (bo+bqo); K=256 concat.
// C-layout gives each quad 4 whole rows -> LN reduce = 16-lane shfl only.
// ---------------------------------------------------------------------------
__global__ __launch_bounds__(256) void k_out_ln(
        const ushort* __restrict__ Vm, const ushort* __restrict__ Qm,
        const ushort* __restrict__ WcT, const ushort* __restrict__ WqoT,
        const float* __restrict__ bo, const float* __restrict__ bqo,
        const float* __restrict__ gamma, const float* __restrict__ beta,
        float* __restrict__ Y) {
    const int tid = threadIdx.x;
    const int w = tid >> 6, lane = tid & 63;
    const int quad = lane >> 4, l16 = lane & 15;
    const int wrow0 = blockIdx.x * 64 + w * 16;
    const int b = wrow0 >> 12;
    const ushort* WcTb = WcT + (size_t)b * 512 * 128;

    f32x4 acc[32] = {};

#pragma unroll
    for (int k0 = 0; k0 < 256; k0 += 32) {
        const ushort* Asrc = (k0 < 128) ? Vm : Qm;
        const ushort* Bsrc = (k0 < 128) ? WcTb : WqoT;
        const int kk = (k0 < 128) ? k0 : (k0 - 128);
        bf16x8 aF = ld8(&Asrc[(size_t)(wrow0 + l16) * 128 + kk + quad * 8]);
        const int bofs = kk + quad * 8;
#pragma unroll
        for (int j = 0; j < 32; ++j) {
            bf16x8 bF = ld8(&Bsrc[(size_t)(j * 16 + l16) * 128 + bofs]);
            acc[j] = MFMA(aF, bF, acc[j]);
        }
    }

    // bias + row partial sums.  acc[j][r]: row = quad*4+r, col = j*16+l16.
    float s[4] = {0.f, 0.f, 0.f, 0.f}, ss[4] = {0.f, 0.f, 0.f, 0.f};
#pragma unroll
    for (int j = 0; j < 32; ++j) {
        int col = j * 16 + l16;
        float bv = bo[col] + bqo[col];
#pragma unroll
        for (int r = 0; r < 4; ++r) {
            float x = acc[j][r] + bv;
            acc[j][r] = x;
            s[r] += x; ss[r] += x * x;
        }
    }
#pragma unroll
    for (int off = 1; off < 16; off <<= 1)
#pragma unroll
        for (int r = 0; r < 4; ++r) {
            s[r]  += __shfl_xor(s[r],  off, 64);
            ss[r] += __shfl_xor(ss[r], off, 64);
        }
    float mu[4], rs[4];
#pragma unroll
    for (int r = 0; r < 4; ++r) {
        mu[r] = s[r] * (1.f / 512.f);
        float var = ss[r] * (1.f / 512.f) - mu[r] * mu[r];
        rs[r] = rsqrtf(var + 1e-5f);
    }
    const int rbase = wrow0 + quad * 4;
#pragma unroll
    for (int j = 0; j < 32; ++j) {
        int col = j * 16 + l16;
        float g = gamma[col], be = beta[col];
#pragma unroll
        for (int r = 0; r < 4; ++r)
            Y[(size_t)(rbase + r) * 512 + col] = (acc[j][r] - mu[r]) * rs[r] * g + be;
    }
}

// ---------------------------------------------------------------------------
extern "C" void kernel_launch(void* const* d_in, const int* in_sizes, int n_in,
                              void* d_out, int out_size, void* d_ws, size_t ws_size,
                              hipStream_t stream) {
    const float* Qin   = (const float*)d_in[0];
    const float* KVin  = (const float*)d_in[1];
    const float* Wq    = (const float*)d_in[2];
    const float* bq    = (const float*)d_in[3];
    const float* Wk    = (const float*)d_in[4];
    const float* bk    = (const float*)d_in[5];
    const float* Wv    = (const float*)d_in[6];
    const float* bv    = (const float*)d_in[7];
    const float* Wo    = (const float*)d_in[8];
    const float* bo    = (const float*)d_in[9];
    const float* Wqo   = (const float*)d_in[10];
    const float* bqo   = (const float*)d_in[11];
    const float* gamma = (const float*)d_in[12];
    const float* beta  = (const float*)d_in[13];
    float* out = (float*)d_out;           // [y (16*4096*512) | attn (16*4*32*32)]
    float* attnOut = out + 33554432;

    char* ws = (char*)d_ws;
    ushort* WqThi = (ushort*)(ws);
    ushort* WqTlo = (ushort*)(ws + 131072);
    ushort* WkThi = (ushort*)(ws + 262144);
    ushort* WkTlo = (ushort*)(ws + 393216);
    ushort* WvT   = (ushort*)(ws + 524288);
    ushort* WqoT  = (ushort*)(ws + 655360);
    ushort* WoB   = (ushort*)(ws + 786432);
    float*  QmF   = (float*) (ws + 917504);
    float*  KmF   = (float*) (ws + 34471936);
    ushort* QmB   = (ushort*)(ws + 68026368);
    ushort* VmB   = (ushort*)(ws + 84803584);
    float*  part  = (float*) (ws + 101580800);   // 64*64*1024*4 = 16,777,216 B
    ushort* WcT   = (ushort*)(ws + 118358016);
    // total ws use: 120,455,168 bytes

    k_prep<<<1280, 256, 0, stream>>>(Wq, Wk, Wv, Wqo, Wo,
                                     WqThi, WqTlo, WkThi, WkTlo, WvT, WqoT, WoB);
    k_proj_q<<<1024, 256, 0, stream>>>(Qin, WqThi, WqTlo, bq, QmF, QmB);
    k_proj_kv<<<1024, 256, 0, stream>>>(KVin, WkThi, WkTlo, WvT, bk, bv, KmF, VmB);
    k_scores<<<dim3(16, 64), 256, 0, stream>>>(QmF, KmF, part);
    k_attn<<<64, 256, 0, stream>>>(part, WoB, attnOut, WcT);
    k_out_ln<<<1024, 256, 0, stream>>>(VmB, QmB, WcT, WqoT, bo, bqo, gamma, beta, out);
}